// Round 2
// baseline (164.991 us; speedup 1.0000x reference)
//
#include <hip/hip_runtime.h>

// GAT aggregation: B=8,S=512,N=32,H=256,V=100001
// out[b,s,:] = sum_c softmax_c( leakyrelu( [src;cand_c]·a_w + a_b ) + mask ) * cand_c
// One wave per (b,s) position; lane holds 4 consecutive H-elements (float4).

constexpr int H  = 256;
constexpr int NN = 32;        // neighbors
constexpr int C  = NN + 1;    // candidates: self + neighbors
constexpr float SLOPE = 0.2f;
constexpr float NEGV  = -1e9f;

__device__ __forceinline__ float wave_sum(float v) {
#pragma unroll
  for (int off = 32; off > 0; off >>= 1)
    v += __shfl_xor(v, off, 64);
  return v;
}

__global__ __launch_bounds__(256, 2) void gat_kernel(
    const int*   __restrict__ node_ids,   // [npos]
    const int*   __restrict__ neighs,     // [npos, NN]
    const int*   __restrict__ mask,       // [npos, NN]
    const float* __restrict__ emb,        // [V, H]
    const float* __restrict__ a_w,        // [2H]
    const float* __restrict__ a_b,        // [1]
    float*       __restrict__ out,        // [npos, H]
    int npos)
{
  const int wid  = (blockIdx.x * blockDim.x + threadIdx.x) >> 6;
  const int lane = threadIdx.x & 63;
  if (wid >= npos) return;
  const int pos = wid;
  const int l4  = lane << 2;

  const float4 aw1 = *(const float4*)(a_w + l4);       // src half of a_w
  const float4 aw2 = *(const float4*)(a_w + H + l4);   // candidate half
  const float  ab  = a_b[0];

  // Gather indices (wave-uniform loads; HW broadcasts)
  int idx[C];
  idx[0] = node_ids[pos];
#pragma unroll
  for (int n = 0; n < NN; ++n) idx[n + 1] = neighs[pos * NN + n];

  // Load all 33 candidate rows once into registers (132 VGPRs)
  float4 e[C];
#pragma unroll
  for (int c = 0; c < C; ++c)
    e[c] = *(const float4*)(emb + (size_t)idx[c] * H + l4);

  // Per-lane partial of src·aw1 (shared by every candidate; folded in
  // before reduction so reduce(zsrc + p_c) = src·aw1 + cand_c·aw2)
  const float zsrc = e[0].x * aw1.x + e[0].y * aw1.y +
                     e[0].z * aw1.z + e[0].w * aw1.w;

  float att[C];
#pragma unroll
  for (int c = 0; c < C; ++c) {
    float p = zsrc + e[c].x * aw2.x + e[c].y * aw2.y +
                     e[c].z * aw2.z + e[c].w * aw2.w;
    att[c] = wave_sum(p);   // all lanes get the full dot product
  }

  // LeakyReLU + mask (self at c=0 never masked)
#pragma unroll
  for (int c = 0; c < C; ++c) {
    float z = att[c] + ab;
    float a = (z > 0.f) ? z : SLOPE * z;
    if (c > 0) a += mask[pos * NN + (c - 1)] ? NEGV : 0.f;
    att[c] = a;
  }

  // Softmax over 33 candidates (wave-uniform, computed redundantly per lane)
  float m = att[0];
#pragma unroll
  for (int c = 1; c < C; ++c) m = fmaxf(m, att[c]);
  float s = 0.f;
#pragma unroll
  for (int c = 0; c < C; ++c) { att[c] = __expf(att[c] - m); s += att[c]; }
  const float inv = 1.f / s;

  // Weighted aggregate from registers
  float4 acc = {0.f, 0.f, 0.f, 0.f};
#pragma unroll
  for (int c = 0; c < C; ++c) {
    const float w = att[c] * inv;
    acc.x += w * e[c].x;
    acc.y += w * e[c].y;
    acc.z += w * e[c].z;
    acc.w += w * e[c].w;
  }
  *(float4*)(out + (size_t)pos * H + l4) = acc;
}

extern "C" void kernel_launch(void* const* d_in, const int* in_sizes, int n_in,
                              void* d_out, int out_size, void* d_ws, size_t ws_size,
                              hipStream_t stream) {
  const int*   node_ids = (const int*)d_in[0];
  const int*   neighs   = (const int*)d_in[1];
  const int*   mask     = (const int*)d_in[2];
  const float* emb      = (const float*)d_in[3];
  const float* a_w      = (const float*)d_in[4];
  const float* a_b      = (const float*)d_in[5];
  float*       out      = (float*)d_out;

  const int npos = in_sizes[0];           // B*S = 4096
  const int waves_per_block = 256 / 64;   // 4 positions per block
  const int grid = (npos + waves_per_block - 1) / waves_per_block;

  gat_kernel<<<grid, 256, 0, stream>>>(node_ids, neighs, mask, emb, a_w, a_b,
                                       out, npos);
}

// Round 4
// 158.402 us; speedup vs baseline: 1.0416x; 1.0416x over previous
//
#include <hip/hip_runtime.h>
#include <math.h>

// GAT aggregation: B=8,S=512,N=32,H=256,V=100001
// One wave per (b,s) position; lane holds 4 consecutive H-elements.
// Online-softmax streaming: each candidate row is loaded once (8-deep
// prefetch ring), dotted, reduced, folded into running (m, s, acc), and
// discarded -> ~80 VGPRs instead of ~220, 4 waves/EU, whole problem
// co-resident in one occupancy round.

constexpr int H  = 256;
constexpr int NN = 32;        // neighbors
constexpr int C  = NN + 1;    // candidates: self + neighbors
constexpr int PF = 8;         // prefetch ring depth (8 x float4 = 32 VGPRs)
constexpr float SLOPE = 0.2f;
constexpr float NEGV  = -1e9f;

__device__ __forceinline__ float wave_sum(float v) {
#pragma unroll
  for (int off = 32; off > 0; off >>= 1)
    v += __shfl_xor(v, off, 64);
  return v;
}

__global__ __launch_bounds__(256, 4) void gat_kernel(
    const int*   __restrict__ node_ids,   // [npos]
    const int*   __restrict__ neighs,     // [npos, NN]
    const int*   __restrict__ mask,       // [npos, NN]
    const float* __restrict__ emb,        // [V, H]
    const float* __restrict__ a_w,        // [2H]
    const float* __restrict__ a_b,        // [1]
    float*       __restrict__ out,        // [npos, H]
    int npos)
{
  const int wid  = (blockIdx.x * blockDim.x + threadIdx.x) >> 6;
  const int lane = threadIdx.x & 63;
  if (wid >= npos) return;
  const int l4 = lane << 2;

  const float4 aw1 = *(const float4*)(a_w + l4);       // src half of a_w
  const float4 aw2 = *(const float4*)(a_w + H + l4);   // candidate half
  const float  ab  = a_b[0];

  // Lane-parallel index/mask gather: lane 0 = self, lanes 1..32 = neighbors
  // (one coalesced load instead of 33 broadcast loads).
  int   my_idx  = 0;
  float my_madd = 0.f;
  if (lane == 0) {
    my_idx = node_ids[wid];
  } else if (lane <= NN) {
    my_idx  = neighs[wid * NN + lane - 1];
    my_madd = mask[wid * NN + lane - 1] ? NEGV : 0.f;
  }

  const float4* __restrict__ embv = (const float4*)emb;  // row = H/4 float4

  // Candidate-c row fragment for this lane, with scalarized (SGPR) row base:
  // address = s[base] + lane*16 -> no per-candidate vector address math.
  auto row_lane = [&](int c) -> float4 {
    int ic = __builtin_amdgcn_readfirstlane(__shfl(my_idx, c, 64));
    return embv[(size_t)ic * (H / 4) + lane];
  };

  float4 buf[PF];
#pragma unroll
  for (int i = 0; i < PF; ++i) buf[i] = row_lane(i);

  float  m = -1e30f, s = 0.f;   // finite "−inf": exp underflows cleanly to 0
  float  zsrc = 0.f;
  float4 acc = {0.f, 0.f, 0.f, 0.f};

#pragma unroll
  for (int c = 0; c < C; ++c) {
    const float4 cur = buf[c & (PF - 1)];
    if (c + PF < C) buf[c & (PF - 1)] = row_lane(c + PF);

    float p = cur.x * aw2.x + cur.y * aw2.y + cur.z * aw2.z + cur.w * aw2.w;
    if (c == 0) {
      float ps = cur.x * aw1.x + cur.y * aw1.y + cur.z * aw1.z + cur.w * aw1.w;
      zsrc = wave_sum(ps);      // src·aw1, shared by every candidate
    }
    float z = zsrc + wave_sum(p) + ab;
    float a = (z > 0.f) ? z : SLOPE * z;          // LeakyReLU(0.2)
    a += __shfl(my_madd, c, 64);                  // mask add (c=0 -> 0)

    // Online softmax update (all values wave-uniform after wave_sum)
    const float mnew  = fmaxf(m, a);
    const float scale = __expf(m - mnew);
    const float pr    = __expf(a - mnew);
    s = s * scale + pr;
    acc.x = acc.x * scale + pr * cur.x;
    acc.y = acc.y * scale + pr * cur.y;
    acc.z = acc.z * scale + pr * cur.z;
    acc.w = acc.w * scale + pr * cur.w;
    m = mnew;
  }

  const float inv = 1.f / s;
  float4 o = {acc.x * inv, acc.y * inv, acc.z * inv, acc.w * inv};
  *(float4*)(out + (size_t)wid * H + l4) = o;
}

extern "C" void kernel_launch(void* const* d_in, const int* in_sizes, int n_in,
                              void* d_out, int out_size, void* d_ws, size_t ws_size,
                              hipStream_t stream) {
  const int*   node_ids = (const int*)d_in[0];
  const int*   neighs   = (const int*)d_in[1];
  const int*   mask     = (const int*)d_in[2];
  const float* emb      = (const float*)d_in[3];
  const float* a_w      = (const float*)d_in[4];
  const float* a_b      = (const float*)d_in[5];
  float*       out      = (float*)d_out;

  const int npos = in_sizes[0];           // B*S = 4096
  const int waves_per_block = 256 / 64;   // 4 positions per block
  const int grid = (npos + waves_per_block - 1) / waves_per_block;

  gat_kernel<<<grid, 256, 0, stream>>>(node_ids, neighs, mask, emb, a_w, a_b,
                                       out, npos);
}